// Round 4
// baseline (4972.356 us; speedup 1.0000x reference)
//
#include <hip/hip_runtime.h>
#include <stdint.h>

#define N_NODES 100000
#define N_EDGES 3200000
#define D_FEAT 256
#define CHUNK 6400
#define NBLK_E 500            // N_EDGES / CHUNK, exact
#define CT 640                // threads for chunk kernels (10 waves), CHUNK/CT=10 exact
#define NB1 25                // super-buckets: row >> 12
#define NB2 1563              // fine buckets:  row >> 6 (64 rows each)

typedef __attribute__((ext_vector_type(8))) short short8;
typedef __attribute__((ext_vector_type(8))) ushort ushort8;
typedef __attribute__((ext_vector_type(4))) float float4v;

__device__ inline unsigned short f2bf(float f) {
    union { float f; unsigned u; } v; v.f = f;
    unsigned u = v.u;
    u += 0x7FFF + ((u >> 16) & 1);   // round-to-nearest-even
    return (unsigned short)(u >> 16);
}
__device__ inline float bf2f(unsigned short u) {
    union { unsigned u; float f; } v; v.u = (unsigned)u << 16;
    return v.f;
}

// ---- W fp32 -> bf16 ------------------------------------------------------
__global__ void wconv_kernel(const float* __restrict__ W, ushort* __restrict__ Wbf) {
    int i = blockIdx.x * 256 + threadIdx.x;
    Wbf[i] = f2bf(W[i]);
}

// ---- GEMM first: y = x @ W^T (projection and aggregation commute) --------
__global__ __launch_bounds__(256) void gemm_x_kernel(
        const float* __restrict__ x,      // [N][256] fp32
        const ushort* __restrict__ Wbf,   // [256][256] bf16, n-major
        ushort* __restrict__ ybf) {       // [N][256] bf16
    int w    = threadIdx.x >> 6;
    int lane = threadIdx.x & 63;
    int quad = lane >> 4;
    int l16  = lane & 15;
    int rt   = blockIdx.x * 64;           // 1563 blocks

    float4v acc[4][4];
    #pragma unroll
    for (int mt = 0; mt < 4; ++mt)
        #pragma unroll
        for (int nt = 0; nt < 4; ++nt) acc[mt][nt] = (float4v){0.f, 0.f, 0.f, 0.f};

    #pragma unroll
    for (int k0 = 0; k0 < 256; k0 += 32) {
        short8 a[4], bf[4];
        #pragma unroll
        for (int mt = 0; mt < 4; ++mt) {
            int row = rt + mt * 16 + l16;
            if (row >= N_NODES) row = N_NODES - 1;   // clamp (tail block)
            const float4v* p = (const float4v*)&x[(size_t)row * 256 + k0 + quad * 8];
            float4v f0 = p[0], f1 = p[1];
            a[mt][0] = (short)f2bf(f0.x); a[mt][1] = (short)f2bf(f0.y);
            a[mt][2] = (short)f2bf(f0.z); a[mt][3] = (short)f2bf(f0.w);
            a[mt][4] = (short)f2bf(f1.x); a[mt][5] = (short)f2bf(f1.y);
            a[mt][6] = (short)f2bf(f1.z); a[mt][7] = (short)f2bf(f1.w);
        }
        #pragma unroll
        for (int nt = 0; nt < 4; ++nt) {
            int n = w * 64 + nt * 16 + l16;
            bf[nt] = *(const short8*)&Wbf[n * 256 + k0 + quad * 8];
        }
        #pragma unroll
        for (int mt = 0; mt < 4; ++mt)
            #pragma unroll
            for (int nt = 0; nt < 4; ++nt)
                acc[mt][nt] = __builtin_amdgcn_mfma_f32_16x16x32_bf16(a[mt], bf[nt], acc[mt][nt], 0, 0, 0);
    }
    #pragma unroll
    for (int mt = 0; mt < 4; ++mt)
        #pragma unroll
        for (int nt = 0; nt < 4; ++nt) {
            int n = w * 64 + nt * 16 + l16;
            #pragma unroll
            for (int r = 0; r < 4; ++r) {
                int row = rt + mt * 16 + quad * 4 + r;   // C/D: col=lane&15, row=quad*4+reg
                if (row < N_NODES) ybf[(size_t)row * 256 + n] = f2bf(acc[mt][nt][r]);
            }
        }
}

// ---- L1 hist: 25 super-buckets per chunk (random input, plain atomics) ---
__global__ __launch_bounds__(CT) void hist1_kernel(const int* __restrict__ erow,
                                                   int* __restrict__ hist) {
    __shared__ int cnt[NB1];
    if (threadIdx.x < NB1) cnt[threadIdx.x] = 0;
    __syncthreads();
    int cb = blockIdx.x * CHUNK;
    #pragma unroll
    for (int j = 0; j < CHUNK; j += CT)
        atomicAdd(&cnt[erow[cb + j + threadIdx.x] >> 12], 1);
    __syncthreads();
    if (threadIdx.x < NB1) hist[blockIdx.x * NB1 + threadIdx.x] = cnt[threadIdx.x];
}

// ---- L2 hist over grouped stream: wave-aggregated (input has long runs) --
__global__ __launch_bounds__(CT) void hist2_kernel(const ushort* __restrict__ rh1,
                                                   int* __restrict__ hist) {
    __shared__ int cnt[NB2];
    for (int b = threadIdx.x; b < NB2; b += CT) cnt[b] = 0;
    __syncthreads();
    int lane = threadIdx.x & 63;
    int cb = blockIdx.x * CHUNK;
    #pragma unroll
    for (int j = 0; j < CHUNK; j += CT) {
        int bin = rh1[cb + j + threadIdx.x];
        int prev = __shfl_up(bin, 1);
        bool leader = (lane == 0) || (bin != prev);
        unsigned long long lb = __ballot(leader);
        if (leader) {
            unsigned long long above = (lane == 63) ? 0ull : (lb & (~0ull << (lane + 1)));
            int next = above ? (__ffsll((unsigned long long)above) - 1) : 64;
            atomicAdd(&cnt[bin], next - lane);
        }
    }
    __syncthreads();
    for (int b = threadIdx.x; b < NB2; b += CT)
        hist[blockIdx.x * NB2 + b] = cnt[b];
}

// ---- per-bucket exclusive scan over 500 chunk entries; emit totals -------
__global__ __launch_bounds__(512) void scan_blocks(int* __restrict__ hist,
                                                   int* __restrict__ totals,
                                                   int nbkt) {
    __shared__ int s[512];
    int b = blockIdx.x;          // bucket
    int t = threadIdx.x;
    int v = (t < NBLK_E) ? hist[t * nbkt + b] : 0;
    s[t] = v;
    __syncthreads();
    for (int o = 1; o < 512; o <<= 1) {
        int x = (t >= o) ? s[t - o] : 0;
        __syncthreads();
        s[t] += x;
        __syncthreads();
    }
    if (t < NBLK_E) hist[t * nbkt + b] = s[t] - v;   // exclusive within bucket
    if (t == NBLK_E - 1) totals[b] = s[t];
}

// ---- generic single-block exclusive scan, n <= 2048 ----------------------
__global__ __launch_bounds__(1024) void scan_small(const int* __restrict__ in,
                                                   int* __restrict__ out, int n) {
    __shared__ int s[2048];
    int t = threadIdx.x;
    int v0 = (t < n) ? in[t] : 0;
    int v1 = (t + 1024 < n) ? in[t + 1024] : 0;
    s[t] = v0; s[t + 1024] = v1;
    __syncthreads();
    // scan lower half (thread t owns slot t)
    for (int o = 1; o < 1024; o <<= 1) {
        int x = (t >= o) ? s[t - o] : 0;
        __syncthreads();
        s[t] += x;
        __syncthreads();
    }
    // scan upper half (thread t owns slot 1024+t)
    for (int o = 1; o < 1024; o <<= 1) {
        int x = (t >= o) ? s[1024 + t - o] : 0;
        __syncthreads();
        s[1024 + t] += x;
        __syncthreads();
    }
    int lowtot = s[1023];
    __syncthreads();
    if (t < n) out[t] = s[t] - v0;
    if (t + 1024 < n) out[t + 1024] = s[1024 + t] + lowtot - v1;
    if (t == 0) out[n] = N_EDGES;
}

// ---- L1 scatter: group by super-bucket; emit bin sidecar + payload -------
__global__ __launch_bounds__(CT) void scatter1_kernel(
        const int* __restrict__ erow, const int* __restrict__ ecol,
        const float* __restrict__ eval,
        const int* __restrict__ hist1, const int* __restrict__ base1,
        ushort* __restrict__ rh1, uint2* __restrict__ cv1) {
    __shared__ int lbase[NB1];
    __shared__ int cnt[NB1];
    int t = threadIdx.x;
    if (t < NB1) {
        lbase[t] = hist1[blockIdx.x * NB1 + t] + base1[t];
        cnt[t] = 0;
    }
    __syncthreads();
    int cb = blockIdx.x * CHUNK;
    #pragma unroll
    for (int j = 0; j < CHUNK; j += CT) {
        int i = cb + j + t;
        int r = erow[i];
        int b = r >> 12;
        int pos = lbase[b] + atomicAdd(&cnt[b], 1);
        rh1[pos] = (unsigned short)(r >> 6);                 // fine bucket id
        uint2 cv;
        cv.x = (unsigned)ecol[i] | ((unsigned)(r & 63) << 17);  // col < 2^17
        union { float f; unsigned u; } w; w.f = eval[i];
        cv.y = w.u;
        cv1[pos] = cv;
    }
}

// ---- L2 scatter: grouped stream -> 1563 buckets, wave-aggregated claims --
__global__ __launch_bounds__(CT) void scatter2_kernel(
        const ushort* __restrict__ rh1, const uint2* __restrict__ cv1,
        const int* __restrict__ hist2, const int* __restrict__ base2,
        uint2* __restrict__ csr) {
    __shared__ int lbase[NB2];
    __shared__ int cnt[NB2];
    for (int b = threadIdx.x; b < NB2; b += CT) {
        lbase[b] = hist2[blockIdx.x * NB2 + b] + base2[b];
        cnt[b] = 0;
    }
    __syncthreads();
    int lane = threadIdx.x & 63;
    int cb = blockIdx.x * CHUNK;
    #pragma unroll
    for (int j = 0; j < CHUNK; j += CT) {
        int i = cb + j + threadIdx.x;
        int bin = rh1[i];
        uint2 v = cv1[i];
        int prev = __shfl_up(bin, 1);
        bool leader = (lane == 0) || (bin != prev);
        unsigned long long lb = __ballot(leader);
        unsigned long long le = lb & (~0ull >> (63 - lane));   // leaders at lanes <= mine
        int start = 63 - __clzll(le);                           // my run's leader lane
        int base = 0;
        if (leader) {
            unsigned long long above = (lane == 63) ? 0ull : (lb & (~0ull << (lane + 1)));
            int next = above ? (__ffsll((unsigned long long)above) - 1) : 64;
            base = atomicAdd(&cnt[bin], next - lane);
        }
        base = __shfl(base, start);
        int pos = lbase[bin] + base + (lane - start);
        csr[pos] = v;
    }
}

// ---- SpMM: one block per 64-row bucket, LDS fp32 accumulation ------------
// Wave per edge; lane l owns d = 4l..4l+3. Accumulator slot layout
// slot(d) = (d&3)*64 + d/4  -> ds_add lane-stride = 1 dword (conflict-free).
__global__ __launch_bounds__(1024, 8) void spmm_kernel(
        const ushort* __restrict__ ybf,           // [N][256] bf16
        const int* __restrict__ base2,            // [NB2+1] bucket edge ranges
        const uint2* __restrict__ csr,            // {col | (row&63)<<17, val}
        float* __restrict__ out) {                // [N][256] fp32
    __shared__ float acc[64 * 256];               // 64 KB
    int t = threadIdx.x;
    #pragma unroll
    for (int j = 0; j < 16; ++j) acc[t + j * 1024] = 0.f;
    __syncthreads();

    int wave = t >> 6;
    int lane = t & 63;
    int s0 = base2[blockIdx.x];
    int s1 = base2[blockIdx.x + 1];

    int e = s0 + wave;
    for (; e + 48 < s1; e += 64) {                // 4 edges per wave-iter (MLP)
        uint2 c0 = csr[e], c1 = csr[e + 16], c2 = csr[e + 32], c3 = csr[e + 48];
        ushort4 y0 = *(const ushort4*)&ybf[(size_t)(c0.x & 0x1FFFF) * 256 + lane * 4];
        ushort4 y1 = *(const ushort4*)&ybf[(size_t)(c1.x & 0x1FFFF) * 256 + lane * 4];
        ushort4 y2 = *(const ushort4*)&ybf[(size_t)(c2.x & 0x1FFFF) * 256 + lane * 4];
        ushort4 y3 = *(const ushort4*)&ybf[(size_t)(c3.x & 0x1FFFF) * 256 + lane * 4];
        union { unsigned u; float f; } w0, w1, w2, w3;
        w0.u = c0.y; w1.u = c1.y; w2.u = c2.y; w3.u = c3.y;
        int r0 = (c0.x >> 17) & 63, r1 = (c1.x >> 17) & 63;
        int r2 = (c2.x >> 17) & 63, r3 = (c3.x >> 17) & 63;
        atomicAdd(&acc[r0 * 256 + 0 * 64 + lane], w0.f * bf2f(y0.x));
        atomicAdd(&acc[r0 * 256 + 1 * 64 + lane], w0.f * bf2f(y0.y));
        atomicAdd(&acc[r0 * 256 + 2 * 64 + lane], w0.f * bf2f(y0.z));
        atomicAdd(&acc[r0 * 256 + 3 * 64 + lane], w0.f * bf2f(y0.w));
        atomicAdd(&acc[r1 * 256 + 0 * 64 + lane], w1.f * bf2f(y1.x));
        atomicAdd(&acc[r1 * 256 + 1 * 64 + lane], w1.f * bf2f(y1.y));
        atomicAdd(&acc[r1 * 256 + 2 * 64 + lane], w1.f * bf2f(y1.z));
        atomicAdd(&acc[r1 * 256 + 3 * 64 + lane], w1.f * bf2f(y1.w));
        atomicAdd(&acc[r2 * 256 + 0 * 64 + lane], w2.f * bf2f(y2.x));
        atomicAdd(&acc[r2 * 256 + 1 * 64 + lane], w2.f * bf2f(y2.y));
        atomicAdd(&acc[r2 * 256 + 2 * 64 + lane], w2.f * bf2f(y2.z));
        atomicAdd(&acc[r2 * 256 + 3 * 64 + lane], w2.f * bf2f(y2.w));
        atomicAdd(&acc[r3 * 256 + 0 * 64 + lane], w3.f * bf2f(y3.x));
        atomicAdd(&acc[r3 * 256 + 1 * 64 + lane], w3.f * bf2f(y3.y));
        atomicAdd(&acc[r3 * 256 + 2 * 64 + lane], w3.f * bf2f(y3.z));
        atomicAdd(&acc[r3 * 256 + 3 * 64 + lane], w3.f * bf2f(y3.w));
    }
    for (; e < s1; e += 16) {
        uint2 c = csr[e];
        ushort4 y = *(const ushort4*)&ybf[(size_t)(c.x & 0x1FFFF) * 256 + lane * 4];
        union { unsigned u; float f; } w; w.u = c.y;
        int r = (c.x >> 17) & 63;
        atomicAdd(&acc[r * 256 + 0 * 64 + lane], w.f * bf2f(y.x));
        atomicAdd(&acc[r * 256 + 1 * 64 + lane], w.f * bf2f(y.y));
        atomicAdd(&acc[r * 256 + 2 * 64 + lane], w.f * bf2f(y.z));
        atomicAdd(&acc[r * 256 + 3 * 64 + lane], w.f * bf2f(y.w));
    }
    __syncthreads();

    // writeout: thread t -> row t>>4, d-range (t&15)*16 .. +15 (coalesced)
    int row = blockIdx.x * 64 + (t >> 4);
    if (row < N_NODES) {
        int rl = t >> 4;
        int dbase = (t & 15) * 16;
        #pragma unroll
        for (int q = 0; q < 4; ++q) {
            float4v o;
            o.x = acc[rl * 256 + 0 * 64 + (dbase >> 2) + q];
            o.y = acc[rl * 256 + 1 * 64 + (dbase >> 2) + q];
            o.z = acc[rl * 256 + 2 * 64 + (dbase >> 2) + q];
            o.w = acc[rl * 256 + 3 * 64 + (dbase >> 2) + q];
            *(float4v*)&out[(size_t)row * 256 + dbase + q * 4] = o;
        }
    }
}

// ---- launch --------------------------------------------------------------

extern "C" void kernel_launch(void* const* d_in, const int* in_sizes, int n_in,
                              void* d_out, int out_size, void* d_ws, size_t ws_size,
                              hipStream_t stream) {
    const float* x    = (const float*)d_in[0];
    const int*   erow = (const int*)d_in[1];
    const int*   ecol = (const int*)d_in[2];
    const float* eval = (const float*)d_in[3];
    const float* W    = (const float*)d_in[4];
    float* out = (float*)d_out;

    char* ws = (char*)d_ws;
    size_t off = 0;
    int* hist1   = (int*)(ws + off);   off += ((size_t)NBLK_E * NB1 * 4 + 255) & ~255ull;
    int* hist2   = (int*)(ws + off);   off += ((size_t)NBLK_E * NB2 * 4 + 255) & ~255ull;
    int* totals1 = (int*)(ws + off);   off += (512 * 4);
    int* base1   = (int*)(ws + off);   off += (512 * 4);
    int* totals2 = (int*)(ws + off);   off += ((size_t)(NB2 + 1) * 4 + 255) & ~255ull;
    int* base2   = (int*)(ws + off);   off += ((size_t)(NB2 + 1) * 4 + 255) & ~255ull;
    ushort* rh1  = (ushort*)(ws + off); off += ((size_t)N_EDGES * 2 + 255) & ~255ull;
    uint2* cv1   = (uint2*)(ws + off);  off += (size_t)N_EDGES * 8;
    uint2* csr   = (uint2*)(ws + off);  off += (size_t)N_EDGES * 8;
    ushort* Wbf  = (ushort*)(ws + off); off += (size_t)D_FEAT * D_FEAT * 2;
    ushort* ybf  = (ushort*)(ws + off); off += (size_t)N_NODES * D_FEAT * 2;

    // projection first: y = x @ W^T
    wconv_kernel<<<(D_FEAT * D_FEAT) / 256, 256, 0, stream>>>(W, Wbf);
    gemm_x_kernel<<<(N_NODES + 63) / 64, 256, 0, stream>>>(x, Wbf, ybf);

    // group edges into 1563 64-row buckets: 25-super -> 1563-fine
    hist1_kernel<<<NBLK_E, CT, 0, stream>>>(erow, hist1);
    scan_blocks<<<NB1, 512, 0, stream>>>(hist1, totals1, NB1);
    scan_small<<<1, 1024, 0, stream>>>(totals1, base1, NB1);
    scatter1_kernel<<<NBLK_E, CT, 0, stream>>>(erow, ecol, eval, hist1, base1, rh1, cv1);
    hist2_kernel<<<NBLK_E, CT, 0, stream>>>(rh1, hist2);
    scan_blocks<<<NB2, 512, 0, stream>>>(hist2, totals2, NB2);
    scan_small<<<1, 1024, 0, stream>>>(totals2, base2, NB2);
    scatter2_kernel<<<NBLK_E, CT, 0, stream>>>(rh1, cv1, hist2, base2, csr);

    // aggregate projected features (LDS fp32 accumulators) -> fp32 output
    spmm_kernel<<<NB2, 1024, 0, stream>>>(ybf, base2, csr, out);
}

// Round 6
// 570.161 us; speedup vs baseline: 8.7210x; 8.7210x over previous
//
#include <hip/hip_runtime.h>
#include <stdint.h>

#define N_NODES 100000
#define N_EDGES 3200000
#define D_FEAT 256
#define CHUNK 8192
#define NBLK_E 391            // ceil(N_EDGES / CHUNK)
#define NBKT 391              // row >> 8 buckets (256 rows each)
#define CT 1024               // threads for chunk kernels (16 waves)

typedef __attribute__((ext_vector_type(8))) short short8;
typedef __attribute__((ext_vector_type(8))) ushort ushort8;
typedef __attribute__((ext_vector_type(4))) float float4v;

__device__ inline unsigned short f2bf(float f) {
    union { float f; unsigned u; } v; v.f = f;
    unsigned u = v.u;
    u += 0x7FFF + ((u >> 16) & 1);   // round-to-nearest-even
    return (unsigned short)(u >> 16);
}
__device__ inline float bf2f(unsigned short u) {
    union { unsigned u; float f; } v; v.u = (unsigned)u << 16;
    return v.f;
}

// ---- W fp32 -> bf16 ------------------------------------------------------
__global__ void wconv_kernel(const float* __restrict__ W, ushort* __restrict__ Wbf) {
    int i = blockIdx.x * 256 + threadIdx.x;
    Wbf[i] = f2bf(W[i]);
}

// ---- GEMM first: y = x @ W^T (projection and aggregation commute) --------
__global__ __launch_bounds__(256) void gemm_x_kernel(
        const float* __restrict__ x,      // [N][256] fp32
        const ushort* __restrict__ Wbf,   // [256][256] bf16, n-major
        ushort* __restrict__ ybf) {       // [N][256] bf16
    int w    = threadIdx.x >> 6;
    int lane = threadIdx.x & 63;
    int quad = lane >> 4;
    int l16  = lane & 15;
    int rt   = blockIdx.x * 64;           // 1563 blocks

    float4v acc[4][4];
    #pragma unroll
    for (int mt = 0; mt < 4; ++mt)
        #pragma unroll
        for (int nt = 0; nt < 4; ++nt) acc[mt][nt] = (float4v){0.f, 0.f, 0.f, 0.f};

    #pragma unroll
    for (int k0 = 0; k0 < 256; k0 += 32) {
        short8 a[4], bf[4];
        #pragma unroll
        for (int mt = 0; mt < 4; ++mt) {
            int row = rt + mt * 16 + l16;
            if (row >= N_NODES) row = N_NODES - 1;   // clamp (tail block)
            const float4v* p = (const float4v*)&x[(size_t)row * 256 + k0 + quad * 8];
            float4v f0 = p[0], f1 = p[1];
            a[mt][0] = (short)f2bf(f0.x); a[mt][1] = (short)f2bf(f0.y);
            a[mt][2] = (short)f2bf(f0.z); a[mt][3] = (short)f2bf(f0.w);
            a[mt][4] = (short)f2bf(f1.x); a[mt][5] = (short)f2bf(f1.y);
            a[mt][6] = (short)f2bf(f1.z); a[mt][7] = (short)f2bf(f1.w);
        }
        #pragma unroll
        for (int nt = 0; nt < 4; ++nt) {
            int n = w * 64 + nt * 16 + l16;
            bf[nt] = *(const short8*)&Wbf[n * 256 + k0 + quad * 8];
        }
        #pragma unroll
        for (int mt = 0; mt < 4; ++mt)
            #pragma unroll
            for (int nt = 0; nt < 4; ++nt)
                acc[mt][nt] = __builtin_amdgcn_mfma_f32_16x16x32_bf16(a[mt], bf[nt], acc[mt][nt], 0, 0, 0);
    }
    #pragma unroll
    for (int mt = 0; mt < 4; ++mt)
        #pragma unroll
        for (int nt = 0; nt < 4; ++nt) {
            int n = w * 64 + nt * 16 + l16;
            #pragma unroll
            for (int r = 0; r < 4; ++r) {
                int row = rt + mt * 16 + quad * 4 + r;   // C/D: col=lane&15, row=quad*4+reg
                if (row < N_NODES) ybf[(size_t)row * 256 + n] = f2bf(acc[mt][nt][r]);
            }
        }
}

// ---- hist: 391 buckets (row>>8) per 8192-edge chunk, 1024 threads --------
__global__ __launch_bounds__(CT) void hist_kernel(const int* __restrict__ erow,
                                                  int* __restrict__ hist) {
    __shared__ int cnt[NBKT];
    if (threadIdx.x < NBKT) cnt[threadIdx.x] = 0;
    __syncthreads();
    int cb = blockIdx.x * CHUNK;
    #pragma unroll
    for (int j = 0; j < CHUNK; j += CT) {
        int i = cb + j + threadIdx.x;
        if (i < N_EDGES) atomicAdd(&cnt[erow[i] >> 8], 1);
    }
    __syncthreads();
    if (threadIdx.x < NBKT) hist[blockIdx.x * NBKT + threadIdx.x] = cnt[threadIdx.x];
}

// ---- per-bucket exclusive scan over chunk entries; emit totals -----------
__global__ __launch_bounds__(512) void scan_blocks(int* __restrict__ hist,
                                                   int* __restrict__ totals) {
    __shared__ int s[512];
    int b = blockIdx.x;          // bucket
    int t = threadIdx.x;
    int v = (t < NBLK_E) ? hist[t * NBKT + b] : 0;
    s[t] = v;
    __syncthreads();
    for (int o = 1; o < 512; o <<= 1) {
        int x = (t >= o) ? s[t - o] : 0;
        __syncthreads();
        s[t] += x;
        __syncthreads();
    }
    if (t < NBLK_E) hist[t * NBKT + b] = s[t] - v;   // exclusive within bucket
    if (t == NBLK_E - 1) totals[b] = s[t];
}

// ---- exclusive scan of bucket totals -> bucket bases ---------------------
__global__ __launch_bounds__(512) void scan_buckets(const int* __restrict__ totals,
                                                    int* __restrict__ base_,
                                                    int* __restrict__ row_start) {
    __shared__ int s[512];
    int t = threadIdx.x;
    int v = (t < NBKT) ? totals[t] : 0;
    s[t] = v;
    __syncthreads();
    for (int o = 1; o < 512; o <<= 1) {
        int x = (t >= o) ? s[t - o] : 0;
        __syncthreads();
        s[t] += x;
        __syncthreads();
    }
    if (t < NBKT) base_[t] = s[t] - v;
    if (t == 0) { base_[NBKT] = N_EDGES; row_start[N_NODES] = N_EDGES; }
}

// ---- scatter: raw edges -> 391 bucket-grouped tmp, 1024 threads ----------
__global__ __launch_bounds__(CT) void scatter_kernel(
        const int* __restrict__ erow, const int* __restrict__ ecol,
        const float* __restrict__ eval,
        const int* __restrict__ hist, const int* __restrict__ base_,
        uint2* __restrict__ tmp) {
    __shared__ int lbase[NBKT];
    __shared__ int cnt[NBKT];
    int t = threadIdx.x;
    if (t < NBKT) {
        lbase[t] = hist[blockIdx.x * NBKT + t] + base_[t];
        cnt[t] = 0;
    }
    __syncthreads();
    int cb = blockIdx.x * CHUNK;
    #pragma unroll
    for (int j = 0; j < CHUNK; j += CT) {
        int i = cb + j + t;
        if (i < N_EDGES) {
            int r = erow[i];
            int b = r >> 8;
            int pos = lbase[b] + atomicAdd(&cnt[b], 1);
            uint2 cv;
            cv.x = (unsigned)ecol[i] | ((unsigned)(r & 255) << 17);  // col < 2^17
            union { float f; unsigned u; } w; w.f = eval[i];
            cv.y = w.u;
            tmp[pos] = cv;
        }
    }
}

// ---- fine counting sort within each 256-row bucket; final CSR ------------
// 512 threads; scatter window is 64 KB (L2-resident) -> full-line writebacks.
__global__ __launch_bounds__(512) void fine_sort(const uint2* __restrict__ tmp,
                                                 const int* __restrict__ base_,
                                                 uint2* __restrict__ csr,
                                                 int* __restrict__ row_start) {
    __shared__ int cnt[256];
    __shared__ int excl[256];
    int b = blockIdx.x;
    int t = threadIdx.x;
    int s0 = base_[b];
    int nb = base_[b + 1] - s0;
    if (t < 256) cnt[t] = 0;
    __syncthreads();
    for (int j = t; j < nb; j += 512)
        atomicAdd(&cnt[tmp[s0 + j].x >> 17], 1);
    __syncthreads();
    int v = 0;
    if (t < 256) { v = cnt[t]; excl[t] = v; }
    __syncthreads();
    for (int o = 1; o < 256; o <<= 1) {
        int x = 0;
        if (t >= o && t < 256) x = excl[t - o];
        __syncthreads();
        if (t < 256) excl[t] += x;
        __syncthreads();
    }
    if (t < 256) {
        int ex = excl[t] - v;            // exclusive prefix for row_low == t
        int row = b * 256 + t;
        if (row < N_NODES) row_start[row] = s0 + ex;
        excl[t] = ex;                    // own-slot overwrite, safe
        cnt[t] = 0;                      // reuse as cursor
    }
    __syncthreads();
    for (int j = t; j < nb; j += 512) {
        uint2 cv = tmp[s0 + j];
        unsigned rl = cv.x >> 17;
        int dst = s0 + excl[rl] + atomicAdd(&cnt[rl], 1);
        csr[dst] = cv;
    }
}

// ---- SpMM over projected y: one wave per row, half-wave per edge ---------
__global__ __launch_bounds__(256) void spmm_kernel(
        const ushort* __restrict__ ybf,           // [N][256] bf16
        const int* __restrict__ row_start,
        const uint2* __restrict__ csr_cv,         // col in low 17 bits of .x
        float* __restrict__ out) {                // [N][256] fp32
    int row  = (blockIdx.x * blockDim.x + threadIdx.x) >> 6;
    int lane = threadIdx.x & 63;
    int half = lane >> 5;
    int hl   = lane & 31;
    if (row >= N_NODES) return;
    int start = row_start[row];
    int end   = row_start[row + 1];
    float acc[8] = {0.f, 0.f, 0.f, 0.f, 0.f, 0.f, 0.f, 0.f};
    int e = start + half;
    for (; e + 6 < end; e += 8) {                 // 4 edges per half-wave iter
        uint2 cv0 = csr_cv[e];
        uint2 cv1 = csr_cv[e + 2];
        uint2 cv2 = csr_cv[e + 4];
        uint2 cv3 = csr_cv[e + 6];
        ushort8 v0 = *(const ushort8*)&ybf[(size_t)(cv0.x & 0x1FFFF) * 256 + hl * 8];
        ushort8 v1 = *(const ushort8*)&ybf[(size_t)(cv1.x & 0x1FFFF) * 256 + hl * 8];
        ushort8 v2 = *(const ushort8*)&ybf[(size_t)(cv2.x & 0x1FFFF) * 256 + hl * 8];
        ushort8 v3 = *(const ushort8*)&ybf[(size_t)(cv3.x & 0x1FFFF) * 256 + hl * 8];
        union { unsigned u; float f; } w0, w1, w2, w3;
        w0.u = cv0.y; w1.u = cv1.y; w2.u = cv2.y; w3.u = cv3.y;
        #pragma unroll
        for (int j = 0; j < 8; ++j) acc[j] += w0.f * bf2f(v0[j]);
        #pragma unroll
        for (int j = 0; j < 8; ++j) acc[j] += w1.f * bf2f(v1[j]);
        #pragma unroll
        for (int j = 0; j < 8; ++j) acc[j] += w2.f * bf2f(v2[j]);
        #pragma unroll
        for (int j = 0; j < 8; ++j) acc[j] += w3.f * bf2f(v3[j]);
    }
    for (; e < end; e += 2) {
        uint2 cv = csr_cv[e];
        ushort8 v = *(const ushort8*)&ybf[(size_t)(cv.x & 0x1FFFF) * 256 + hl * 8];
        union { unsigned u; float f; } w; w.u = cv.y;
        #pragma unroll
        for (int j = 0; j < 8; ++j) acc[j] += w.f * bf2f(v[j]);
    }
    #pragma unroll
    for (int j = 0; j < 8; ++j) acc[j] += __shfl_xor(acc[j], 32, 64);
    if (half == 0) {
        float4v o0 = {acc[0], acc[1], acc[2], acc[3]};
        float4v o1 = {acc[4], acc[5], acc[6], acc[7]};
        *(float4v*)&out[(size_t)row * 256 + hl * 8]     = o0;
        *(float4v*)&out[(size_t)row * 256 + hl * 8 + 4] = o1;
    }
}

// ---- launch --------------------------------------------------------------

extern "C" void kernel_launch(void* const* d_in, const int* in_sizes, int n_in,
                              void* d_out, int out_size, void* d_ws, size_t ws_size,
                              hipStream_t stream) {
    const float* x    = (const float*)d_in[0];
    const int*   erow = (const int*)d_in[1];
    const int*   ecol = (const int*)d_in[2];
    const float* eval = (const float*)d_in[3];
    const float* W    = (const float*)d_in[4];
    float* out = (float*)d_out;

    char* ws = (char*)d_ws;
    size_t off = 0;
    int* hist      = (int*)(ws + off);   off += ((size_t)NBLK_E * NBKT * 4 + 255) & ~255ull;
    int* totals    = (int*)(ws + off);   off += (512 * 4);
    int* base_     = (int*)(ws + off);   off += ((size_t)(NBKT + 1) * 4 + 255) & ~255ull;
    int* row_start = (int*)(ws + off);   off += ((size_t)(N_NODES + 1) * 4 + 255) & ~255ull;
    uint2* tmp     = (uint2*)(ws + off); off += (size_t)N_EDGES * 8;
    uint2* csr     = (uint2*)(ws + off); off += (size_t)N_EDGES * 8;
    ushort* Wbf    = (ushort*)(ws + off); off += (size_t)D_FEAT * D_FEAT * 2;
    ushort* ybf    = (ushort*)(ws + off); off += (size_t)N_NODES * D_FEAT * 2;

    // projection first: y = x @ W^T
    wconv_kernel<<<(D_FEAT * D_FEAT) / 256, 256, 0, stream>>>(W, Wbf);
    gemm_x_kernel<<<(N_NODES + 63) / 64, 256, 0, stream>>>(x, Wbf, ybf);

    // single-level CSR build: hist -> scans -> scatter -> fine sort
    hist_kernel<<<NBLK_E, CT, 0, stream>>>(erow, hist);
    scan_blocks<<<NBKT, 512, 0, stream>>>(hist, totals);
    scan_buckets<<<1, 512, 0, stream>>>(totals, base_, row_start);
    scatter_kernel<<<NBLK_E, CT, 0, stream>>>(erow, ecol, eval, hist, base_, tmp);
    fine_sort<<<NBKT, 512, 0, stream>>>(tmp, base_, csr, row_start);

    // aggregate projected features straight into the fp32 output
    spmm_kernel<<<N_NODES / 4, 256, 0, stream>>>(ybf, row_start, csr, out);
}